// Round 3
// baseline (158.319 us; speedup 1.0000x reference)
//
#include <hip/hip_runtime.h>

// LPSC cell: per-row tiny MLP. c == 0.0 in the reference, so the g-branch
// (wfa/wfb/wfc) is dead: new_S = Y + (-Y + k1*x1 - k2*x2) exactly.
// R2 lesson: weight reads from LDS (~430 ds_read/thread) were the stall
// source (VALUBusy 40%, HBM 22%, dur 52us). Weights are wave-uniform ->
// read them straight from global with uniform indices so the compiler
// emits s_load into SGPRs (scalar cache broadcast, zero VALU/LDS cost).

#define LDIM 5
#define HDIM 16

constexpr int BLOCK = 256;
constexpr int R = 4;  // consecutive rows per thread -> all loads/stores dwordx4

__global__ __launch_bounds__(BLOCK) void lpsc_kernel(
    const float* __restrict__ inputs,  // (B,2)
    const float* __restrict__ Zin,     // (B,5)
    const float* __restrict__ Yin,     // (B,1)
    const float* __restrict__ A,       // (5,5)
    const float* __restrict__ w2a,     // (5,16)
    const float* __restrict__ b2a,     // (16,)
    const float* __restrict__ w2b,     // (16,16)
    const float* __restrict__ b2b,     // (16,)
    const float* __restrict__ w2c,     // (16,2)
    const float* __restrict__ b2c,     // (2,)
    float* __restrict__ out,           // [B: newS][5B: newZ][B: newS]
    int B)
{
    const int t = threadIdx.x;
    const long long g = (long long)blockIdx.x * BLOCK + t;  // thread id
    const long long r0 = g * R;                             // first of 4 rows
    if (r0 >= B) return;
    const bool full = (r0 + R <= B);

    float z[R][LDIM];
    float x1[R], x2[R], y[R];

    if (full) {
        // inputs: 8 consecutive floats
        const float4 iv0 = reinterpret_cast<const float4*>(inputs)[g * 2 + 0];
        const float4 iv1 = reinterpret_cast<const float4*>(inputs)[g * 2 + 1];
        x1[0] = iv0.x; x2[0] = iv0.y; x1[1] = iv0.z; x2[1] = iv0.w;
        x1[2] = iv1.x; x2[2] = iv1.y; x1[3] = iv1.z; x2[3] = iv1.w;
        // Y: 4 consecutive floats
        const float4 yv = reinterpret_cast<const float4*>(Yin)[g];
        y[0] = yv.x; y[1] = yv.y; y[2] = yv.z; y[3] = yv.w;
        // Z: 20 consecutive floats
        float zf[R * LDIM];
        #pragma unroll
        for (int q = 0; q < 5; ++q) {
            const float4 zv = reinterpret_cast<const float4*>(Zin)[g * 5 + q];
            zf[q * 4 + 0] = zv.x; zf[q * 4 + 1] = zv.y;
            zf[q * 4 + 2] = zv.z; zf[q * 4 + 3] = zv.w;
        }
        #pragma unroll
        for (int r = 0; r < R; ++r)
            #pragma unroll
            for (int k = 0; k < LDIM; ++k) z[r][k] = zf[r * LDIM + k];
    } else {
        #pragma unroll
        for (int r = 0; r < R; ++r) {
            long long rr = (r0 + r < B) ? (r0 + r) : (long long)(B - 1);
            x1[r] = inputs[rr * 2 + 0];
            x2[r] = inputs[rr * 2 + 1];
            y[r]  = Yin[rr];
            #pragma unroll
            for (int k = 0; k < LDIM; ++k) z[r][k] = Zin[rr * LDIM + k];
        }
    }

    // new_Z = Z @ A   (A[k*5+j] is wave-uniform -> s_load)
    float nz[R][LDIM];
    #pragma unroll
    for (int r = 0; r < R; ++r)
        #pragma unroll
        for (int j = 0; j < LDIM; ++j) nz[r][j] = 0.0f;
    #pragma unroll
    for (int k = 0; k < LDIM; ++k)
        #pragma unroll
        for (int j = 0; j < LDIM; ++j) {
            const float a = A[k * LDIM + j];
            #pragma unroll
            for (int r = 0; r < R; ++r) nz[r][j] = fmaf(z[r][k], a, nz[r][j]);
        }

    // h = relu(new_Z @ w2a + b2a)
    float h[R][HDIM];
    #pragma unroll
    for (int r = 0; r < R; ++r)
        #pragma unroll
        for (int j = 0; j < HDIM; ++j) h[r][j] = b2a[j];
    #pragma unroll
    for (int k = 0; k < LDIM; ++k)
        #pragma unroll
        for (int j = 0; j < HDIM; ++j) {
            const float w = w2a[k * HDIM + j];
            #pragma unroll
            for (int r = 0; r < R; ++r) h[r][j] = fmaf(nz[r][k], w, h[r][j]);
        }
    #pragma unroll
    for (int r = 0; r < R; ++r)
        #pragma unroll
        for (int j = 0; j < HDIM; ++j) h[r][j] = fmaxf(h[r][j], 0.0f);

    // g2 = relu(h @ w2b + b2b)
    float g2[R][HDIM];
    #pragma unroll
    for (int r = 0; r < R; ++r)
        #pragma unroll
        for (int j = 0; j < HDIM; ++j) g2[r][j] = b2b[j];
    #pragma unroll
    for (int k = 0; k < HDIM; ++k)
        #pragma unroll
        for (int j = 0; j < HDIM; ++j) {
            const float w = w2b[k * HDIM + j];
            #pragma unroll
            for (int r = 0; r < R; ++r) g2[r][j] = fmaf(h[r][k], w, g2[r][j]);
        }
    #pragma unroll
    for (int r = 0; r < R; ++r)
        #pragma unroll
        for (int j = 0; j < HDIM; ++j) g2[r][j] = fmaxf(g2[r][j], 0.0f);

    // K = |g2 @ w2c + b2c|
    float k1[R], k2[R];
    #pragma unroll
    for (int r = 0; r < R; ++r) { k1[r] = b2c[0]; k2[r] = b2c[1]; }
    #pragma unroll
    for (int k = 0; k < HDIM; ++k) {
        const float w0 = w2c[k * 2 + 0];
        const float w1 = w2c[k * 2 + 1];
        #pragma unroll
        for (int r = 0; r < R; ++r) {
            k1[r] = fmaf(g2[r][k], w0, k1[r]);
            k2[r] = fmaf(g2[r][k], w1, k2[r]);
        }
    }

    float ns[R];
    #pragma unroll
    for (int r = 0; r < R; ++r) {
        const float K1 = fabsf(k1[r]);
        const float K2 = fabsf(k2[r]);
        // DY = -Y + k1*x1 - k2*x2 (+ 0*g); new_S = Y + DY (ref op order)
        const float dy = -y[r] + K1 * x1[r] - K2 * x2[r];
        ns[r] = y[r] + dy;
    }

    if (full) {
        float4 nsv = make_float4(ns[0], ns[1], ns[2], ns[3]);
        reinterpret_cast<float4*>(out)[g] = nsv;
        reinterpret_cast<float4*>(out + (long long)6 * B)[g] = nsv;
        float zf[R * LDIM];
        #pragma unroll
        for (int r = 0; r < R; ++r)
            #pragma unroll
            for (int j = 0; j < LDIM; ++j) zf[r * LDIM + j] = nz[r][j];
        #pragma unroll
        for (int q = 0; q < 5; ++q) {
            reinterpret_cast<float4*>(out + (long long)B)[g * 5 + q] =
                make_float4(zf[q * 4 + 0], zf[q * 4 + 1], zf[q * 4 + 2], zf[q * 4 + 3]);
        }
    } else {
        #pragma unroll
        for (int r = 0; r < R; ++r) {
            const long long row = r0 + r;
            if (row < B) {
                out[row] = ns[r];
                out[(long long)6 * B + row] = ns[r];
                #pragma unroll
                for (int j = 0; j < LDIM; ++j)
                    out[(long long)B + row * LDIM + j] = nz[r][j];
            }
        }
    }
}

extern "C" void kernel_launch(void* const* d_in, const int* in_sizes, int n_in,
                              void* d_out, int out_size, void* d_ws, size_t ws_size,
                              hipStream_t stream) {
    const float* inputs = (const float*)d_in[0];
    const float* Zin    = (const float*)d_in[1];
    const float* Yin    = (const float*)d_in[2];
    const float* A      = (const float*)d_in[3];
    const float* w2a    = (const float*)d_in[4];
    const float* b2a    = (const float*)d_in[5];
    const float* w2b    = (const float*)d_in[6];
    const float* b2b    = (const float*)d_in[7];
    const float* w2c    = (const float*)d_in[8];
    const float* b2c    = (const float*)d_in[9];

    const int B = in_sizes[2];  // Y has B elements
    const int rowsPerBlock = BLOCK * R;
    const int grid = (B + rowsPerBlock - 1) / rowsPerBlock;

    lpsc_kernel<<<grid, BLOCK, 0, stream>>>(inputs, Zin, Yin, A, w2a, b2a,
                                            w2b, b2b, w2c, b2c,
                                            (float*)d_out, B);
}

// Round 7
// 145.376 us; speedup vs baseline: 1.0890x; 1.0890x over previous
//
#include <hip/hip_runtime.h>

// LPSC cell. c == 0.0 => g-branch (wfa/wfb/wfc) dead: new_S = Y + (-Y + k1*x1 - k2*x2).
// R3 analysis (corrected for SIMD-32): VALU ~25% real busy, HBM 22%, occupancy ~1.9
// waves/SIMD -> latency-stall bound. Lever: more resident parallelism, less serial
// work per thread. R=2 rows/thread, 4096 blocks, scalar FMA (SGPR weight operands),
// 32-bit indexing, non-temporal stores (outputs are write-once).
// R6 fix: __builtin_nontemporal_store needs a clang ext_vector type, not HIP float2.

#define LDIM 5
#define HDIM 16
constexpr int BLOCK = 256;

typedef float f32x2 __attribute__((ext_vector_type(2)));
typedef float f32x4 __attribute__((ext_vector_type(4)));

__device__ __forceinline__ void lpsc_row(
    const float* __restrict__ z,      // 5 inputs for this row
    const float* __restrict__ A,
    const float* __restrict__ w2a, const float* __restrict__ b2a,
    const float* __restrict__ w2b, const float* __restrict__ b2b,
    const float* __restrict__ w2c, const float* __restrict__ b2c,
    float x1, float x2, float y,
    float* __restrict__ nz_out, float* __restrict__ ns_out)
{
    float nz[LDIM];
    #pragma unroll
    for (int j = 0; j < LDIM; ++j) nz[j] = 0.0f;
    #pragma unroll
    for (int k = 0; k < LDIM; ++k)
        #pragma unroll
        for (int j = 0; j < LDIM; ++j)
            nz[j] = fmaf(z[k], A[k * LDIM + j], nz[j]);

    float h[HDIM];
    #pragma unroll
    for (int j = 0; j < HDIM; ++j) h[j] = b2a[j];
    #pragma unroll
    for (int k = 0; k < LDIM; ++k)
        #pragma unroll
        for (int j = 0; j < HDIM; ++j)
            h[j] = fmaf(nz[k], w2a[k * HDIM + j], h[j]);
    #pragma unroll
    for (int j = 0; j < HDIM; ++j) h[j] = fmaxf(h[j], 0.0f);

    float g2[HDIM];
    #pragma unroll
    for (int j = 0; j < HDIM; ++j) g2[j] = b2b[j];
    #pragma unroll
    for (int k = 0; k < HDIM; ++k)
        #pragma unroll
        for (int j = 0; j < HDIM; ++j)
            g2[j] = fmaf(h[k], w2b[k * HDIM + j], g2[j]);
    #pragma unroll
    for (int j = 0; j < HDIM; ++j) g2[j] = fmaxf(g2[j], 0.0f);

    float k1 = b2c[0], k2 = b2c[1];
    #pragma unroll
    for (int k = 0; k < HDIM; ++k) {
        k1 = fmaf(g2[k], w2c[k * 2 + 0], k1);
        k2 = fmaf(g2[k], w2c[k * 2 + 1], k2);
    }
    const float K1 = fabsf(k1);
    const float K2 = fabsf(k2);
    // DY = -Y + k1*x1 - k2*x2 (+ 0*g); new_S = Y + DY (reference op order)
    *ns_out = y + (-y + K1 * x1 - K2 * x2);
    #pragma unroll
    for (int j = 0; j < LDIM; ++j) nz_out[j] = nz[j];
}

__global__ __launch_bounds__(BLOCK) void lpsc_main(
    const float* __restrict__ inputs,  // (B,2)
    const float* __restrict__ Zin,     // (B,5)
    const float* __restrict__ Yin,     // (B,1)
    const float* __restrict__ A,
    const float* __restrict__ w2a, const float* __restrict__ b2a,
    const float* __restrict__ w2b, const float* __restrict__ b2b,
    const float* __restrict__ w2c, const float* __restrict__ b2c,
    float* __restrict__ out,           // [B: newS][5B: newZ][B: newS]
    unsigned B, unsigned pairs)
{
    const unsigned g = blockIdx.x * (unsigned)BLOCK + threadIdx.x;  // row-pair id
    if (g >= pairs) return;

    // loads: all float2/float4, issued up front
    const f32x4 iv = reinterpret_cast<const f32x4*>(inputs)[g];   // x1,x2 for 2 rows
    const f32x2 yv = reinterpret_cast<const f32x2*>(Yin)[g];
    float zl[2 * LDIM];
    const f32x2* zp = reinterpret_cast<const f32x2*>(Zin) + (size_t)g * LDIM;
    #pragma unroll
    for (int q = 0; q < LDIM; ++q) {
        const f32x2 v = zp[q];
        zl[2 * q] = v.x;
        zl[2 * q + 1] = v.y;
    }

    float nz0[LDIM], nz1[LDIM], ns0, ns1;
    lpsc_row(&zl[0],    A, w2a, b2a, w2b, b2b, w2c, b2c, iv.x, iv.y, yv.x, nz0, &ns0);
    lpsc_row(&zl[LDIM], A, w2a, b2a, w2b, b2b, w2c, b2c, iv.z, iv.w, yv.y, nz1, &ns1);

    // non-temporal stores: outputs are write-once, keep caches clean
    const f32x2 nsv = {ns0, ns1};
    __builtin_nontemporal_store(nsv, reinterpret_cast<f32x2*>(out) + g);
    __builtin_nontemporal_store(nsv, reinterpret_cast<f32x2*>(out + (size_t)6 * B) + g);
    f32x2* oz = reinterpret_cast<f32x2*>(out + (size_t)B) + (size_t)g * LDIM;
    const f32x2 z0 = {nz0[0], nz0[1]};
    const f32x2 z1 = {nz0[2], nz0[3]};
    const f32x2 z2 = {nz0[4], nz1[0]};
    const f32x2 z3 = {nz1[1], nz1[2]};
    const f32x2 z4 = {nz1[3], nz1[4]};
    __builtin_nontemporal_store(z0, oz + 0);
    __builtin_nontemporal_store(z1, oz + 1);
    __builtin_nontemporal_store(z2, oz + 2);
    __builtin_nontemporal_store(z3, oz + 3);
    __builtin_nontemporal_store(z4, oz + 4);
}

// Tail: at most 1 leftover row when B is odd (never hit for B=2^21; kept for safety).
__global__ void lpsc_tail(
    const float* __restrict__ inputs, const float* __restrict__ Zin,
    const float* __restrict__ Yin, const float* __restrict__ A,
    const float* __restrict__ w2a, const float* __restrict__ b2a,
    const float* __restrict__ w2b, const float* __restrict__ b2b,
    const float* __restrict__ w2c, const float* __restrict__ b2c,
    float* __restrict__ out, unsigned B, unsigned start)
{
    const unsigned row = start + blockIdx.x * blockDim.x + threadIdx.x;
    if (row >= B) return;
    float z[LDIM];
    #pragma unroll
    for (int k = 0; k < LDIM; ++k) z[k] = Zin[(size_t)row * LDIM + k];
    float nz[LDIM], ns;
    lpsc_row(z, A, w2a, b2a, w2b, b2b, w2c, b2c,
             inputs[(size_t)row * 2 + 0], inputs[(size_t)row * 2 + 1], Yin[row],
             nz, &ns);
    out[row] = ns;
    out[(size_t)6 * B + row] = ns;
    #pragma unroll
    for (int j = 0; j < LDIM; ++j) out[(size_t)B + (size_t)row * LDIM + j] = nz[j];
}

extern "C" void kernel_launch(void* const* d_in, const int* in_sizes, int n_in,
                              void* d_out, int out_size, void* d_ws, size_t ws_size,
                              hipStream_t stream) {
    const float* inputs = (const float*)d_in[0];
    const float* Zin    = (const float*)d_in[1];
    const float* Yin    = (const float*)d_in[2];
    const float* A      = (const float*)d_in[3];
    const float* w2a    = (const float*)d_in[4];
    const float* b2a    = (const float*)d_in[5];
    const float* w2b    = (const float*)d_in[6];
    const float* b2b    = (const float*)d_in[7];
    const float* w2c    = (const float*)d_in[8];
    const float* b2c    = (const float*)d_in[9];

    const unsigned B = (unsigned)in_sizes[2];  // Y has B elements
    const unsigned pairs = B / 2;
    const unsigned grid = (pairs + BLOCK - 1) / BLOCK;

    lpsc_main<<<grid, BLOCK, 0, stream>>>(inputs, Zin, Yin, A, w2a, b2a,
                                          w2b, b2b, w2c, b2c,
                                          (float*)d_out, B, pairs);
    if (B & 1u) {
        lpsc_tail<<<1, 64, 0, stream>>>(inputs, Zin, Yin, A, w2a, b2a,
                                        w2b, b2b, w2c, b2c,
                                        (float*)d_out, B, pairs * 2);
    }
}

// Round 8
// 143.704 us; speedup vs baseline: 1.1017x; 1.0116x over previous
//
#include <hip/hip_runtime.h>

// LPSC cell. c == 0.0 => g-branch (wfa/wfb/wfc) dead: new_S = Y + (-Y + k1*x1 - k2*x2).
// R7: kernel ~40us (fell below the 40us harness fills in top-5). Next lever: VALU
// issue count. Pack the OUTPUT-NEURON (j) dim into v_pk_fma_f32: weight pairs are
// contiguous (8B-aligned) in w2a/w2b/w2c -> stay wave-uniform SGPR-pair operands;
// activation splat {a,a} hoisted per-k, amortized over 8 packed FMAs.
// (R4's row-packing failed this: it needed a per-weight VGPR splat.)
// Core math per row: ~435 -> ~265 instrs. pk_fma is IEEE-identical per lane.

#define LDIM 5
#define HDIM 16
constexpr int BLOCK = 256;

typedef float f32x2 __attribute__((ext_vector_type(2)));
typedef float f32x4 __attribute__((ext_vector_type(4)));

__device__ __forceinline__ f32x2 fma2(f32x2 a, f32x2 b, f32x2 c) {
    return __builtin_elementwise_fma(a, b, c);
}
__device__ __forceinline__ f32x2 max2(f32x2 a, f32x2 b) {
    return __builtin_elementwise_max(a, b);
}

// One row, j-dimension packed into f32x2 lanes.
__device__ __forceinline__ void lpsc_row(
    const float* __restrict__ z,       // 5 inputs for this row
    const float* __restrict__ A,       // (5,5) scalar
    const f32x2* __restrict__ W1,      // w2a as (5, 8) pairs
    const f32x2* __restrict__ B1,      // b2a as 8 pairs
    const f32x2* __restrict__ W2,      // w2b as (16, 8) pairs
    const f32x2* __restrict__ B2,      // b2b as 8 pairs
    const f32x2* __restrict__ W3,      // w2c as 16 pairs {w0,w1}
    f32x2 b3,                          // b2c
    float x1, float x2, float y,
    float* __restrict__ nz_out, float* __restrict__ ns_out)
{
    // new_Z = Z @ A (5x5, scalar; j=5 odd so packing not worth it)
    float nz[LDIM];
    #pragma unroll
    for (int j = 0; j < LDIM; ++j) nz[j] = 0.0f;
    #pragma unroll
    for (int k = 0; k < LDIM; ++k)
        #pragma unroll
        for (int j = 0; j < LDIM; ++j)
            nz[j] = fmaf(z[k], A[k * LDIM + j], nz[j]);

    // h = relu(nz @ w2a + b2a), 8 packed accumulators
    f32x2 h[HDIM / 2];
    #pragma unroll
    for (int jp = 0; jp < HDIM / 2; ++jp) h[jp] = B1[jp];
    #pragma unroll
    for (int k = 0; k < LDIM; ++k) {
        const f32x2 a2 = {nz[k], nz[k]};
        #pragma unroll
        for (int jp = 0; jp < HDIM / 2; ++jp)
            h[jp] = fma2(a2, W1[k * (HDIM / 2) + jp], h[jp]);
    }
    const f32x2 zero = {0.0f, 0.0f};
    #pragma unroll
    for (int jp = 0; jp < HDIM / 2; ++jp) h[jp] = max2(h[jp], zero);

    // g2 = relu(h @ w2b + b2b)
    f32x2 g2[HDIM / 2];
    #pragma unroll
    for (int jp = 0; jp < HDIM / 2; ++jp) g2[jp] = B2[jp];
    #pragma unroll
    for (int k = 0; k < HDIM; ++k) {
        const float hk = (k & 1) ? h[k >> 1].y : h[k >> 1].x;  // static index
        const f32x2 a2 = {hk, hk};
        #pragma unroll
        for (int jp = 0; jp < HDIM / 2; ++jp)
            g2[jp] = fma2(a2, W2[k * (HDIM / 2) + jp], g2[jp]);
    }
    #pragma unroll
    for (int jp = 0; jp < HDIM / 2; ++jp) g2[jp] = max2(g2[jp], zero);

    // {k1,k2} = g2 @ w2c + b2c, packed pair accumulator
    f32x2 k12 = b3;
    #pragma unroll
    for (int k = 0; k < HDIM; ++k) {
        const float gk = (k & 1) ? g2[k >> 1].y : g2[k >> 1].x;
        const f32x2 a2 = {gk, gk};
        k12 = fma2(a2, W3[k], k12);
    }

    const float K1 = fabsf(k12.x);
    const float K2 = fabsf(k12.y);
    // DY = -Y + k1*x1 - k2*x2 (+ 0*g); new_S = Y + DY (reference op order)
    *ns_out = y + (-y + K1 * x1 - K2 * x2);
    #pragma unroll
    for (int j = 0; j < LDIM; ++j) nz_out[j] = nz[j];
}

__global__ __launch_bounds__(BLOCK) void lpsc_main(
    const float* __restrict__ inputs,  // (B,2)
    const float* __restrict__ Zin,     // (B,5)
    const float* __restrict__ Yin,     // (B,1)
    const float* __restrict__ A,
    const float* __restrict__ w2a, const float* __restrict__ b2a,
    const float* __restrict__ w2b, const float* __restrict__ b2b,
    const float* __restrict__ w2c, const float* __restrict__ b2c,
    float* __restrict__ out,           // [B: newS][5B: newZ][B: newS]
    unsigned B, unsigned pairs)
{
    const unsigned g = blockIdx.x * (unsigned)BLOCK + threadIdx.x;  // row-pair id
    if (g >= pairs) return;

    const f32x2* W1 = reinterpret_cast<const f32x2*>(w2a);
    const f32x2* B1 = reinterpret_cast<const f32x2*>(b2a);
    const f32x2* W2 = reinterpret_cast<const f32x2*>(w2b);
    const f32x2* B2 = reinterpret_cast<const f32x2*>(b2b);
    const f32x2* W3 = reinterpret_cast<const f32x2*>(w2c);
    const f32x2  b3 = *reinterpret_cast<const f32x2*>(b2c);

    // loads: all float2/float4, issued up front
    const f32x4 iv = reinterpret_cast<const f32x4*>(inputs)[g];   // x1,x2 for 2 rows
    const f32x2 yv = reinterpret_cast<const f32x2*>(Yin)[g];
    float zl[2 * LDIM];
    const f32x2* zp = reinterpret_cast<const f32x2*>(Zin) + (size_t)g * LDIM;
    #pragma unroll
    for (int q = 0; q < LDIM; ++q) {
        const f32x2 v = zp[q];
        zl[2 * q] = v.x;
        zl[2 * q + 1] = v.y;
    }

    float nz0[LDIM], nz1[LDIM], ns0, ns1;
    lpsc_row(&zl[0],    A, W1, B1, W2, B2, W3, b3, iv.x, iv.y, yv.x, nz0, &ns0);
    lpsc_row(&zl[LDIM], A, W1, B1, W2, B2, W3, b3, iv.z, iv.w, yv.y, nz1, &ns1);

    // non-temporal stores: outputs are write-once, keep caches clean
    const f32x2 nsv = {ns0, ns1};
    __builtin_nontemporal_store(nsv, reinterpret_cast<f32x2*>(out) + g);
    __builtin_nontemporal_store(nsv, reinterpret_cast<f32x2*>(out + (size_t)6 * B) + g);
    f32x2* oz = reinterpret_cast<f32x2*>(out + (size_t)B) + (size_t)g * LDIM;
    const f32x2 z0 = {nz0[0], nz0[1]};
    const f32x2 z1 = {nz0[2], nz0[3]};
    const f32x2 z2 = {nz0[4], nz1[0]};
    const f32x2 z3 = {nz1[1], nz1[2]};
    const f32x2 z4 = {nz1[3], nz1[4]};
    __builtin_nontemporal_store(z0, oz + 0);
    __builtin_nontemporal_store(z1, oz + 1);
    __builtin_nontemporal_store(z2, oz + 2);
    __builtin_nontemporal_store(z3, oz + 3);
    __builtin_nontemporal_store(z4, oz + 4);
}

// Tail: at most 1 leftover row when B is odd (never hit for B=2^21; kept for safety).
__global__ void lpsc_tail(
    const float* __restrict__ inputs, const float* __restrict__ Zin,
    const float* __restrict__ Yin, const float* __restrict__ A,
    const float* __restrict__ w2a, const float* __restrict__ b2a,
    const float* __restrict__ w2b, const float* __restrict__ b2b,
    const float* __restrict__ w2c, const float* __restrict__ b2c,
    float* __restrict__ out, unsigned B, unsigned start)
{
    const unsigned row = start + blockIdx.x * blockDim.x + threadIdx.x;
    if (row >= B) return;
    float z[LDIM];
    #pragma unroll
    for (int k = 0; k < LDIM; ++k) z[k] = Zin[(size_t)row * LDIM + k];
    float nz[LDIM], ns;
    lpsc_row(z, A,
             reinterpret_cast<const f32x2*>(w2a), reinterpret_cast<const f32x2*>(b2a),
             reinterpret_cast<const f32x2*>(w2b), reinterpret_cast<const f32x2*>(b2b),
             reinterpret_cast<const f32x2*>(w2c), *reinterpret_cast<const f32x2*>(b2c),
             inputs[(size_t)row * 2 + 0], inputs[(size_t)row * 2 + 1], Yin[row],
             nz, &ns);
    out[row] = ns;
    out[(size_t)6 * B + row] = ns;
    #pragma unroll
    for (int j = 0; j < LDIM; ++j) out[(size_t)B + (size_t)row * LDIM + j] = nz[j];
}

extern "C" void kernel_launch(void* const* d_in, const int* in_sizes, int n_in,
                              void* d_out, int out_size, void* d_ws, size_t ws_size,
                              hipStream_t stream) {
    const float* inputs = (const float*)d_in[0];
    const float* Zin    = (const float*)d_in[1];
    const float* Yin    = (const float*)d_in[2];
    const float* A      = (const float*)d_in[3];
    const float* w2a    = (const float*)d_in[4];
    const float* b2a    = (const float*)d_in[5];
    const float* w2b    = (const float*)d_in[6];
    const float* b2b    = (const float*)d_in[7];
    const float* w2c    = (const float*)d_in[8];
    const float* b2c    = (const float*)d_in[9];

    const unsigned B = (unsigned)in_sizes[2];  // Y has B elements
    const unsigned pairs = B / 2;
    const unsigned grid = (pairs + BLOCK - 1) / BLOCK;

    lpsc_main<<<grid, BLOCK, 0, stream>>>(inputs, Zin, Yin, A, w2a, b2a,
                                          w2b, b2b, w2c, b2c,
                                          (float*)d_out, B, pairs);
    if (B & 1u) {
        lpsc_tail<<<1, 64, 0, stream>>>(inputs, Zin, Yin, A, w2a, b2a,
                                        w2b, b2b, w2c, b2c,
                                        (float*)d_out, B, pairs * 2);
    }
}

// Round 10
// 142.345 us; speedup vs baseline: 1.1122x; 1.0095x over previous
//
#include <hip/hip_runtime.h>

// LPSC cell. c == 0.0 => g-branch (wfa/wfb/wfc) dead: new_S = Y + (-Y + k1*x1 - k2*x2).
// Ladder: 52.8us (R3 scalar R=4) -> ~40 (R7 R=2+NT) -> ~38 (R8 pk). Instruction-count
// halvings stopped paying => ~25us floor is exposed latency at ~2 waves/SIMD.
// R9: R=1 row/thread — halve per-wave critical path again, 2x waves (32768),
// __launch_bounds__(256,8) caps VGPR<=64 for 8 waves/SIMD. Keep j-dim pk_fma
// packing (weights stay wave-uniform SGPR pairs, splat via op_sel is free).
// (R9 bench was a broker timeout — resubmitting unchanged.)

#define LDIM 5
#define HDIM 16
constexpr int BLOCK = 256;

typedef float f32x2 __attribute__((ext_vector_type(2)));

__device__ __forceinline__ f32x2 fma2(f32x2 a, f32x2 b, f32x2 c) {
    return __builtin_elementwise_fma(a, b, c);
}
__device__ __forceinline__ f32x2 max2(f32x2 a, f32x2 b) {
    return __builtin_elementwise_max(a, b);
}

__global__ __launch_bounds__(BLOCK, 8) void lpsc_main(
    const float* __restrict__ inputs,  // (B,2)
    const float* __restrict__ Zin,     // (B,5)
    const float* __restrict__ Yin,     // (B,1)
    const float* __restrict__ A,       // (5,5)
    const float* __restrict__ w2a, const float* __restrict__ b2a,
    const float* __restrict__ w2b, const float* __restrict__ b2b,
    const float* __restrict__ w2c, const float* __restrict__ b2c,
    float* __restrict__ out,           // [B: newS][5B: newZ][B: newS]
    unsigned B)
{
    const unsigned row = blockIdx.x * (unsigned)BLOCK + threadIdx.x;
    if (row >= B) return;

    const f32x2* W1 = reinterpret_cast<const f32x2*>(w2a);  // (5, 8) pairs
    const f32x2* B1 = reinterpret_cast<const f32x2*>(b2a);
    const f32x2* W2 = reinterpret_cast<const f32x2*>(w2b);  // (16, 8) pairs
    const f32x2* B2 = reinterpret_cast<const f32x2*>(b2b);
    const f32x2* W3 = reinterpret_cast<const f32x2*>(w2c);  // 16 pairs {w0,w1}
    const f32x2  b3 = *reinterpret_cast<const f32x2*>(b2c);

    // Per-row loads. inputs row is 8B-aligned f32x2; Z row is 4B-aligned -> scalar.
    const f32x2 xv = reinterpret_cast<const f32x2*>(inputs)[row];
    const float y = Yin[row];
    float z[LDIM];
    #pragma unroll
    for (int k = 0; k < LDIM; ++k) z[k] = Zin[(size_t)row * LDIM + k];

    // new_Z = Z @ A (5x5 scalar fma; j=5 odd, packing not worth it)
    float nz[LDIM];
    #pragma unroll
    for (int j = 0; j < LDIM; ++j) nz[j] = 0.0f;
    #pragma unroll
    for (int k = 0; k < LDIM; ++k)
        #pragma unroll
        for (int j = 0; j < LDIM; ++j)
            nz[j] = fmaf(z[k], A[k * LDIM + j], nz[j]);

    // h = relu(nz @ w2a + b2a), j packed
    f32x2 h[HDIM / 2];
    #pragma unroll
    for (int jp = 0; jp < HDIM / 2; ++jp) h[jp] = B1[jp];
    #pragma unroll
    for (int k = 0; k < LDIM; ++k) {
        const f32x2 a2 = {nz[k], nz[k]};
        #pragma unroll
        for (int jp = 0; jp < HDIM / 2; ++jp)
            h[jp] = fma2(a2, W1[k * (HDIM / 2) + jp], h[jp]);
    }
    const f32x2 zero = {0.0f, 0.0f};
    #pragma unroll
    for (int jp = 0; jp < HDIM / 2; ++jp) h[jp] = max2(h[jp], zero);

    // g2 = relu(h @ w2b + b2b), j packed
    f32x2 g2[HDIM / 2];
    #pragma unroll
    for (int jp = 0; jp < HDIM / 2; ++jp) g2[jp] = B2[jp];
    #pragma unroll
    for (int k = 0; k < HDIM; ++k) {
        const float hk = (k & 1) ? h[k >> 1].y : h[k >> 1].x;  // static index
        const f32x2 a2 = {hk, hk};
        #pragma unroll
        for (int jp = 0; jp < HDIM / 2; ++jp)
            g2[jp] = fma2(a2, W2[k * (HDIM / 2) + jp], g2[jp]);
    }
    #pragma unroll
    for (int jp = 0; jp < HDIM / 2; ++jp) g2[jp] = max2(g2[jp], zero);

    // {k1,k2} = g2 @ w2c + b2c, packed pair accumulator
    f32x2 k12 = b3;
    #pragma unroll
    for (int k = 0; k < HDIM; ++k) {
        const float gk = (k & 1) ? g2[k >> 1].y : g2[k >> 1].x;
        const f32x2 a2 = {gk, gk};
        k12 = fma2(a2, W3[k], k12);
    }

    const float K1 = fabsf(k12.x);
    const float K2 = fabsf(k12.y);
    // DY = -Y + k1*x1 - k2*x2 (+ 0*g); new_S = Y + DY (reference op order)
    const float ns = y + (-y + K1 * xv.x - K2 * xv.y);

    // Stores: write-once -> non-temporal. ns twice; nz 5 scalars (4B-aligned rows).
    __builtin_nontemporal_store(ns, out + row);
    __builtin_nontemporal_store(ns, out + (size_t)6 * B + row);
    float* oz = out + (size_t)B + (size_t)row * LDIM;
    #pragma unroll
    for (int j = 0; j < LDIM; ++j)
        __builtin_nontemporal_store(nz[j], oz + j);
}

extern "C" void kernel_launch(void* const* d_in, const int* in_sizes, int n_in,
                              void* d_out, int out_size, void* d_ws, size_t ws_size,
                              hipStream_t stream) {
    const float* inputs = (const float*)d_in[0];
    const float* Zin    = (const float*)d_in[1];
    const float* Yin    = (const float*)d_in[2];
    const float* A      = (const float*)d_in[3];
    const float* w2a    = (const float*)d_in[4];
    const float* b2a    = (const float*)d_in[5];
    const float* w2b    = (const float*)d_in[6];
    const float* b2b    = (const float*)d_in[7];
    const float* w2c    = (const float*)d_in[8];
    const float* b2c    = (const float*)d_in[9];

    const unsigned B = (unsigned)in_sizes[2];  // Y has B elements
    const unsigned grid = (B + BLOCK - 1) / BLOCK;

    lpsc_main<<<grid, BLOCK, 0, stream>>>(inputs, Zin, Yin, A, w2a, b2a,
                                          w2b, b2b, w2c, b2c,
                                          (float*)d_out, B);
}

// Round 11
// 142.311 us; speedup vs baseline: 1.1125x; 1.0002x over previous
//
#include <hip/hip_runtime.h>

// LPSC cell. c == 0.0 => g-branch (wfa/wfb/wfc) dead: new_S = Y + (-Y + k1*x1 - k2*x2).
// Ladder: 52.8 (R3) -> ~41 (R7) -> ~39.5 (R8 pk) -> ~38 (R10 R=1). Instruction-count,
// packing, and occupancy levers all bounce off a ~38us floor => suspect external floor:
// NT stores force 57 MB of output through HBM inside the kernel window, but d_out
// (58.7 MB) FITS IN L3 (256 MB) — cached stores drain at L2/L3 speed instead.
// R11: R10 kernel with NT stores -> plain stores. Single-variable A/B.

#define LDIM 5
#define HDIM 16
constexpr int BLOCK = 256;

typedef float f32x2 __attribute__((ext_vector_type(2)));

__device__ __forceinline__ f32x2 fma2(f32x2 a, f32x2 b, f32x2 c) {
    return __builtin_elementwise_fma(a, b, c);
}
__device__ __forceinline__ f32x2 max2(f32x2 a, f32x2 b) {
    return __builtin_elementwise_max(a, b);
}

__global__ __launch_bounds__(BLOCK, 8) void lpsc_main(
    const float* __restrict__ inputs,  // (B,2)
    const float* __restrict__ Zin,     // (B,5)
    const float* __restrict__ Yin,     // (B,1)
    const float* __restrict__ A,       // (5,5)
    const float* __restrict__ w2a, const float* __restrict__ b2a,
    const float* __restrict__ w2b, const float* __restrict__ b2b,
    const float* __restrict__ w2c, const float* __restrict__ b2c,
    float* __restrict__ out,           // [B: newS][5B: newZ][B: newS]
    unsigned B)
{
    const unsigned row = blockIdx.x * (unsigned)BLOCK + threadIdx.x;
    if (row >= B) return;

    const f32x2* W1 = reinterpret_cast<const f32x2*>(w2a);  // (5, 8) pairs
    const f32x2* B1 = reinterpret_cast<const f32x2*>(b2a);
    const f32x2* W2 = reinterpret_cast<const f32x2*>(w2b);  // (16, 8) pairs
    const f32x2* B2 = reinterpret_cast<const f32x2*>(b2b);
    const f32x2* W3 = reinterpret_cast<const f32x2*>(w2c);  // 16 pairs {w0,w1}
    const f32x2  b3 = *reinterpret_cast<const f32x2*>(b2c);

    // Per-row loads. inputs row is 8B-aligned f32x2; Z row is 4B-aligned -> scalar.
    const f32x2 xv = reinterpret_cast<const f32x2*>(inputs)[row];
    const float y = Yin[row];
    float z[LDIM];
    #pragma unroll
    for (int k = 0; k < LDIM; ++k) z[k] = Zin[(size_t)row * LDIM + k];

    // new_Z = Z @ A (5x5 scalar fma; j=5 odd, packing not worth it)
    float nz[LDIM];
    #pragma unroll
    for (int j = 0; j < LDIM; ++j) nz[j] = 0.0f;
    #pragma unroll
    for (int k = 0; k < LDIM; ++k)
        #pragma unroll
        for (int j = 0; j < LDIM; ++j)
            nz[j] = fmaf(z[k], A[k * LDIM + j], nz[j]);

    // h = relu(nz @ w2a + b2a), j packed
    f32x2 h[HDIM / 2];
    #pragma unroll
    for (int jp = 0; jp < HDIM / 2; ++jp) h[jp] = B1[jp];
    #pragma unroll
    for (int k = 0; k < LDIM; ++k) {
        const f32x2 a2 = {nz[k], nz[k]};
        #pragma unroll
        for (int jp = 0; jp < HDIM / 2; ++jp)
            h[jp] = fma2(a2, W1[k * (HDIM / 2) + jp], h[jp]);
    }
    const f32x2 zero = {0.0f, 0.0f};
    #pragma unroll
    for (int jp = 0; jp < HDIM / 2; ++jp) h[jp] = max2(h[jp], zero);

    // g2 = relu(h @ w2b + b2b), j packed
    f32x2 g2[HDIM / 2];
    #pragma unroll
    for (int jp = 0; jp < HDIM / 2; ++jp) g2[jp] = B2[jp];
    #pragma unroll
    for (int k = 0; k < HDIM; ++k) {
        const float hk = (k & 1) ? h[k >> 1].y : h[k >> 1].x;  // static index
        const f32x2 a2 = {hk, hk};
        #pragma unroll
        for (int jp = 0; jp < HDIM / 2; ++jp)
            g2[jp] = fma2(a2, W2[k * (HDIM / 2) + jp], g2[jp]);
    }
    #pragma unroll
    for (int jp = 0; jp < HDIM / 2; ++jp) g2[jp] = max2(g2[jp], zero);

    // {k1,k2} = g2 @ w2c + b2c, packed pair accumulator
    f32x2 k12 = b3;
    #pragma unroll
    for (int k = 0; k < HDIM; ++k) {
        const float gk = (k & 1) ? g2[k >> 1].y : g2[k >> 1].x;
        const f32x2 a2 = {gk, gk};
        k12 = fma2(a2, W3[k], k12);
    }

    const float K1 = fabsf(k12.x);
    const float K2 = fabsf(k12.y);
    // DY = -Y + k1*x1 - k2*x2 (+ 0*g); new_S = Y + DY (reference op order)
    const float ns = y + (-y + K1 * xv.x - K2 * xv.y);

    // Plain cached stores: d_out fits in L3; let L2/L3 absorb and drain lazily.
    out[row] = ns;
    out[(size_t)6 * B + row] = ns;
    float* oz = out + (size_t)B + (size_t)row * LDIM;
    #pragma unroll
    for (int j = 0; j < LDIM; ++j) oz[j] = nz[j];
}

extern "C" void kernel_launch(void* const* d_in, const int* in_sizes, int n_in,
                              void* d_out, int out_size, void* d_ws, size_t ws_size,
                              hipStream_t stream) {
    const float* inputs = (const float*)d_in[0];
    const float* Zin    = (const float*)d_in[1];
    const float* Yin    = (const float*)d_in[2];
    const float* A      = (const float*)d_in[3];
    const float* w2a    = (const float*)d_in[4];
    const float* b2a    = (const float*)d_in[5];
    const float* w2b    = (const float*)d_in[6];
    const float* b2b    = (const float*)d_in[7];
    const float* w2c    = (const float*)d_in[8];
    const float* b2c    = (const float*)d_in[9];

    const unsigned B = (unsigned)in_sizes[2];  // Y has B elements
    const unsigned grid = (B + BLOCK - 1) / BLOCK;

    lpsc_main<<<grid, BLOCK, 0, stream>>>(inputs, Zin, Yin, A, w2a, b2a,
                                          w2b, b2b, w2c, b2c,
                                          (float*)d_out, B);
}